// Round 11
// baseline (725.822 us; speedup 1.0000x reference)
//
#include <hip/hip_runtime.h>
#include <hip/hip_bf16.h>
#include <cstdint>

// B=4, S=4096, E=2048, H=16, D=128 -> 16384 independent tokens.
// qkv = x @ W_qkv (16384x2048x6144); per-token 16x16 head mix;
// out = attn @ W_out + b_out (16384x2048x2048).

#define TOKENS 16384
#define EMB    2048
#define NQKV   6144

typedef __bf16 bf16x8_t  __attribute__((ext_vector_type(8)));
typedef float  f32x16_t  __attribute__((ext_vector_type(16)));

#define GLOAD16(gsrc, ldst)                                                    \
  __builtin_amdgcn_global_load_lds(                                            \
      (const __attribute__((address_space(1))) void*)(uintptr_t)(gsrc),        \
      (__attribute__((address_space(3))) void*)(uint32_t)(uintptr_t)(ldst),    \
      16, 0, 0)

static __device__ __forceinline__ unsigned short f32_to_bf16_bits(float f) {
  union { float f; uint32_t u; } x; x.f = f;
  uint32_t u = x.u;
  u += 0x7fffu + ((u >> 16) & 1u);   // round-to-nearest-even
  return (unsigned short)(u >> 16);
}

// ---------------------------------------------------------------- converts
__global__ __launch_bounds__(256) void cvt_f32_bf16(
    const float4* __restrict__ in, ushort4* __restrict__ out, int n4) {
  const int stride = gridDim.x * blockDim.x;
  for (int i = blockIdx.x * blockDim.x + threadIdx.x; i < n4; i += stride) {
    float4 v = in[i];
    ushort4 o;
    o.x = f32_to_bf16_bits(v.x);
    o.y = f32_to_bf16_bits(v.y);
    o.z = f32_to_bf16_bits(v.z);
    o.w = f32_to_bf16_bits(v.w);
    out[i] = o;
  }
}

// transpose R x C f32 -> C x R bf16
__global__ __launch_bounds__(256) void transpose_cvt(
    const float* __restrict__ in, unsigned short* __restrict__ out, int R, int C) {
  __shared__ float tile[32][33];
  const int bx = blockIdx.x * 32;
  const int by = blockIdx.y * 32;
  const int tx = threadIdx.x;
  const int ty = threadIdx.y;
#pragma unroll
  for (int j = 0; j < 32; j += 8)
    tile[ty + j][tx] = in[(size_t)(by + ty + j) * C + bx + tx];
  __syncthreads();
#pragma unroll
  for (int j = 0; j < 32; j += 8)
    out[(size_t)(bx + ty + j) * R + by + tx] = f32_to_bf16_bits(tile[tx][ty + j]);
}

// ---------------------------------------------------------------- GEMM
// 256x256 tile, BK=64, 8 waves (2M x 4N), mfma_f32_32x32x16_bf16 (floor
// 2066 vs 2483 cyc/tile/CU), LANE-LINEAR LDS geometry: LDS image = 1KB
// groups [rb 0..7][ks 0..3][kg][row']x16B == exactly the gload_lds write
// pattern. Fragment reads are base + lane*16 + imm (zero conflicts, no
// swizzle). Global DMA source is per-lane row-gathered (32 rows x 32B).
// Skeleton = R10 (2 phases, 2 barriers, vmcnt(6)/tile).
template <bool OUT_BF16>
__global__ __launch_bounds__(512, 1) void gemm_bt(
    const unsigned short* __restrict__ A,
    const unsigned short* __restrict__ BT,
    unsigned short* __restrict__ Cb,
    float* __restrict__ Cf,
    const float* __restrict__ bias,
    int M, int N) {
  constexpr int K = 2048;
  constexpr int BK = 64;
  constexpr int NKT = K / BK;          // 32
  __shared__ __align__(16) char lds[131072];  // [2 bufs][A 32KB | B 32KB]

  const int nbx = N / 256;
  const int nwg = gridDim.x;           // % 8 == 0
  const int bid = blockIdx.x;
  const int swzb = (bid & 7) * (nwg >> 3) + (bid >> 3);
  const int by = swzb / nbx;
  const int bx = swzb % nbx;

  const int t    = threadIdx.x;
  const int lane = t & 63;
  const int wid  = t >> 6;             // 0..7
  const int wr   = wid >> 2;           // 0..1 (M)
  const int wc   = wid & 3;            // 0..3 (N)
  const int r31  = lane & 31;          // frag row' (A) / col' (B)
  const int kg   = lane >> 5;          // k-group 0..1

  const unsigned short* aSrc = A  + (size_t)by * 256 * K;
  const unsigned short* bSrc = BT + (size_t)bx * 256 * K;

  // staging: per half h, wave wid issues 2 instrs j; group idx = wid*2+j
  // (rb = idx>>2, ks = idx&3). Lane reads global row (rb*32+r31) bytes
  // [ks*32 + kg*16 .. +15]; LDS dest group = idx*1024 (+h*16KB), lane-linear.
  int offs[2], loff[2];
#pragma unroll
  for (int j = 0; j < 2; ++j) {
    const int idx = wid * 2 + j;
    loff[j] = idx * 1024;
    offs[j] = ((idx >> 2) * 32 + r31) * K + (idx & 3) * 16 + kg * 8;
  }

  auto stageA = [&](int h, int k0, char* bufA) {
#pragma unroll
    for (int j = 0; j < 2; ++j)
      GLOAD16(aSrc + offs[j] + h * (128 * K) + k0, bufA + h * 16384 + loff[j]);
  };
  auto stageB = [&](int h, int k0, char* bufB) {
#pragma unroll
    for (int j = 0; j < 2; ++j)
      GLOAD16(bSrc + offs[j] + h * (128 * K) + k0, bufB + h * 16384 + loff[j]);
  };

  // fragment read bases: group (wr*4+mf, ks) for A; (wc*2+nf, ks) for B.
  const int aBase = wr * 16384 + lane * 16;
  const int bBase = wc * 8192 + lane * 16;

  f32x16_t acc[4][2] = {};
  bf16x8_t av[4][4];                   // [mf][ks]
  bf16x8_t bv[2][4];                   // [nf][ks]

#define RD_ALL(cA_, cB_)                                                       \
  _Pragma("unroll") for (int mf = 0; mf < 4; ++mf)                             \
  _Pragma("unroll") for (int ks = 0; ks < 4; ++ks)                             \
    av[mf][ks] = *(const bf16x8_t*)((cA_) + aBase + mf * 4096 + ks * 1024);    \
  _Pragma("unroll") for (int nf = 0; nf < 2; ++nf)                             \
  _Pragma("unroll") for (int ks = 0; ks < 4; ++ks)                             \
    bv[nf][ks] = *(const bf16x8_t*)((cB_) + bBase + nf * 4096 + ks * 1024);

#define MFMAH(MF0)                                                             \
  _Pragma("unroll") for (int mf = (MF0); mf < (MF0) + 2; ++mf)                 \
  _Pragma("unroll") for (int nf = 0; nf < 2; ++nf)                             \
  _Pragma("unroll") for (int ks = 0; ks < 4; ++ks)                             \
    acc[mf][nf] = __builtin_amdgcn_mfma_f32_32x32x16_bf16(                     \
        av[mf][ks], bv[nf][ks], acc[mf][nf], 0, 0, 0);

#define SBR __builtin_amdgcn_sched_barrier(0)

  // One K-tile: 2 phases, 2 barriers, 1 lgkm drain, 1 counted vmcnt (R10).
#define BODY(KT, S1, S2, VMN)                                                  \
  {                                                                            \
    char* cA = lds + ((KT) & 1) * 65536;                                       \
    char* cB = cA + 32768;                                                     \
    char* nA = lds + (((KT) + 1) & 1) * 65536;                                 \
    const int k1 = ((KT) + 1) * BK, k2 = ((KT) + 2) * BK;                      \
    /* PhA: all 24 reads (covered by prev vmcnt->barrier); stage Ah1(kt+1);    \
       drain; MFMA mf0-1 */                                                    \
    RD_ALL(cA, cB); SBR;                                                       \
    if (S1) { stageA(1, k1, nA); } SBR;                                        \
    asm volatile("s_waitcnt lgkmcnt(0)" ::: "memory"); SBR;                    \
    __builtin_amdgcn_s_setprio(1);                                             \
    MFMAH(0);                                                                  \
    __builtin_amdgcn_s_setprio(0); SBR;                                        \
    __builtin_amdgcn_s_barrier();                                              \
    /* PhB: stage (kt+2) into CURRENT bufs (readers drained at PhA lgkm,       \
       PhA barrier separates -> WAR-safe); MFMA mf2-3; vmcnt; barrier */       \
    if (S2) { stageB(0, k2, cB); stageB(1, k2, cB); stageA(0, k2, cA); } SBR;  \
    __builtin_amdgcn_s_setprio(1);                                             \
    MFMAH(2);                                                                  \
    __builtin_amdgcn_s_setprio(0); SBR;                                        \
    asm volatile("s_waitcnt vmcnt(" #VMN ")" ::: "memory"); SBR;               \
    __builtin_amdgcn_s_barrier();                                              \
  }

  // ---- prologue: tile0 full (8 instr) + tile1 {Bh0,Bh1,Ah0} (6 instr);
  // vmcnt(6) = tile0 landed; barrier.
  {
    char* b0A = lds;
    char* b0B = lds + 32768;
    char* b1A = lds + 65536;
    char* b1B = b1A + 32768;
    stageA(0, 0, b0A); stageA(1, 0, b0A);
    stageB(0, 0, b0B); stageB(1, 0, b0B);
    stageB(0, BK, b1B); stageB(1, BK, b1B);
    stageA(0, BK, b1A);
    asm volatile("s_waitcnt vmcnt(6)" ::: "memory");
    __builtin_amdgcn_s_barrier();
  }

  for (int kt = 0; kt < NKT - 2; ++kt) {
    BODY(kt, 1, 1, 6);
  }
  BODY(NKT - 2, 1, 0, 0);
  BODY(NKT - 1, 0, 0, 0);

  // ---- epilogue: 32x32 C/D map (m74/m101): col = lane&31,
  // row = (reg&3) + 8*(reg>>2) + 4*(lane>>5)
  const int rbase = by * 256 + wr * 128 + 4 * kg;
  const int cbase = bx * 256 + wc * 64 + r31;
#pragma unroll
  for (int mf = 0; mf < 4; ++mf) {
#pragma unroll
    for (int nf = 0; nf < 2; ++nf) {
      const int col = cbase + nf * 32;
#pragma unroll
      for (int reg = 0; reg < 16; ++reg) {
        const int row = rbase + mf * 32 + (reg & 3) + 8 * (reg >> 2);
        const size_t off = (size_t)row * N + col;
        if constexpr (OUT_BF16) {
          Cb[off] = f32_to_bf16_bits(acc[mf][nf][reg]);
        } else {
          Cf[off] = acc[mf][nf][reg] + bias[col];
        }
      }
    }
  }
#undef RD_ALL
#undef MFMAH
#undef SBR
#undef BODY
}

// ---------------------------------------------------------------- attention
__global__ __launch_bounds__(256) void attn_heads(
    const unsigned short* __restrict__ qkv,  // [T][6144] bf16
    unsigned short* __restrict__ attn) {     // [T][2048] bf16
  __shared__ __align__(16) unsigned short sQKV[NQKV];
  __shared__ float sW[16][16];

  const int t = threadIdx.x;
  const size_t qbase = (size_t)blockIdx.x * NQKV;

  const uint4* gp = (const uint4*)(qkv + qbase);
  uint4* l = (uint4*)sQKV;
#pragma unroll
  for (int i = 0; i < 3; ++i) {
    const int idx = i * 256 + t;
    int dst = idx;
    if (idx >= 256 && idx < 512) {
      const int r = (idx - 256) >> 4;
      const int c = idx & 15;
      dst = 256 + r * 16 + (c ^ (r & 7));
    }
    l[dst] = gp[idx];
  }
  __syncthreads();

  const int h = t >> 4;
  const int H = t & 15;
  const bf16x8_t* q8 = (const bf16x8_t*)sQKV + h * 16;
  const bf16x8_t* k8 = (const bf16x8_t*)sQKV + 256;
  float s = 0.f;
#pragma unroll
  for (int d8 = 0; d8 < 16; ++d8) {
    bf16x8_t qv = q8[d8];
    bf16x8_t kv = k8[H * 16 + (d8 ^ (H & 7))];
#pragma unroll
    for (int j = 0; j < 8; ++j)
      s = fmaf((float)qv[j], (float)kv[j], s);
  }
  s *= 0.08838834764831843f;

  float mx = s;
#pragma unroll
  for (int o = 8; o; o >>= 1) mx = fmaxf(mx, __shfl_xor(mx, o));
  const float e = __expf(s - mx);
  float sum = e;
#pragma unroll
  for (int o = 8; o; o >>= 1) sum += __shfl_xor(sum, o);
  sW[h][H] = e / sum;
  __syncthreads();

  const int d0c = t & 15;
  const bf16x8_t* v8 = (const bf16x8_t*)sQKV + 512;
  float accv[8] = {};
#pragma unroll
  for (int j = 0; j < 16; ++j) {
    const float w = sW[h][j];
    const bf16x8_t vv = v8[j * 16 + d0c];
#pragma unroll
    for (int jj = 0; jj < 8; ++jj)
      accv[jj] = fmaf(w, (float)vv[jj], accv[jj]);
  }
  bf16x8_t o;
#pragma unroll
  for (int jj = 0; jj < 8; ++jj) o[jj] = (__bf16)accv[jj];
  *(bf16x8_t*)(attn + (size_t)blockIdx.x * EMB + h * 128 + d0c * 8) = o;
}

// ---------------------------------------------------------------- launch
extern "C" void kernel_launch(void* const* d_in, const int* in_sizes, int n_in,
                              void* d_out, int out_size, void* d_ws, size_t ws_size,
                              hipStream_t stream) {
  const float* x    = (const float*)d_in[0];
  const float* Wqkv = (const float*)d_in[1];
  const float* Wout = (const float*)d_in[2];
  const float* bout = (const float*)d_in[3];
  float* out = (float*)d_out;

  unsigned short* xb    = (unsigned short*)d_ws;          // 33,554,432
  unsigned short* wqkvT = xb    + (size_t)33554432;       // 12,582,912
  unsigned short* woutT = wqkvT + (size_t)12582912;       //  4,194,304
  unsigned short* qkv   = woutT + (size_t)4194304;        // 100,663,296
  unsigned short* attn  = qkv   + (size_t)100663296;      // 33,554,432

  cvt_f32_bf16<<<2048, 256, 0, stream>>>((const float4*)x, (ushort4*)xb, 33554432 / 4);
  transpose_cvt<<<dim3(6144 / 32, 2048 / 32), dim3(32, 8), 0, stream>>>(Wqkv, wqkvT, 2048, 6144);
  transpose_cvt<<<dim3(2048 / 32, 2048 / 32), dim3(32, 8), 0, stream>>>(Wout, woutT, 2048, 2048);
  // qkv = x @ W_qkv : grid 64*24 = 1536 (%8==0)
  gemm_bt<true><<<(16384 / 256) * (6144 / 256), 512, 0, stream>>>(
      xb, wqkvT, qkv, nullptr, nullptr, 16384, 6144);
  attn_heads<<<TOKENS, 256, 0, stream>>>(qkv, attn);
  // out = attn @ W_out + b_out : grid 64*8 = 512 (%8==0)
  gemm_bt<false><<<(16384 / 256) * (2048 / 256), 512, 0, stream>>>(
      attn, woutT, nullptr, out, bout, 16384, 2048);
}

// Round 12
// 612.589 us; speedup vs baseline: 1.1848x; 1.1848x over previous
//
#include <hip/hip_runtime.h>
#include <hip/hip_bf16.h>
#include <cstdint>

// B=4, S=4096, E=2048, H=16, D=128 -> 16384 independent tokens.
// qkv = x @ W_qkv (16384x2048x6144); per-token 16x16 head mix;
// out = attn @ W_out + b_out (16384x2048x2048).

#define TOKENS 16384
#define EMB    2048
#define NQKV   6144

typedef __bf16 bf16x8_t __attribute__((ext_vector_type(8)));
typedef float  f32x4_t  __attribute__((ext_vector_type(4)));

#define GLOAD16(gsrc, ldst)                                                    \
  __builtin_amdgcn_global_load_lds(                                            \
      (const __attribute__((address_space(1))) void*)(uintptr_t)(gsrc),        \
      (__attribute__((address_space(3))) void*)(uint32_t)(uintptr_t)(ldst),    \
      16, 0, 0)

static __device__ __forceinline__ unsigned short f32_to_bf16_bits(float f) {
  union { float f; uint32_t u; } x; x.f = f;
  uint32_t u = x.u;
  u += 0x7fffu + ((u >> 16) & 1u);   // round-to-nearest-even
  return (unsigned short)(u >> 16);
}

// ---------------------------------------------------------------- converts
__global__ __launch_bounds__(256) void cvt_f32_bf16(
    const float4* __restrict__ in, ushort4* __restrict__ out, int n4) {
  const int stride = gridDim.x * blockDim.x;
  for (int i = blockIdx.x * blockDim.x + threadIdx.x; i < n4; i += stride) {
    float4 v = in[i];
    ushort4 o;
    o.x = f32_to_bf16_bits(v.x);
    o.y = f32_to_bf16_bits(v.y);
    o.z = f32_to_bf16_bits(v.z);
    o.w = f32_to_bf16_bits(v.w);
    out[i] = o;
  }
}

// transpose R x C f32 -> C x R bf16
__global__ __launch_bounds__(256) void transpose_cvt(
    const float* __restrict__ in, unsigned short* __restrict__ out, int R, int C) {
  __shared__ float tile[32][33];
  const int bx = blockIdx.x * 32;
  const int by = blockIdx.y * 32;
  const int tx = threadIdx.x;
  const int ty = threadIdx.y;
#pragma unroll
  for (int j = 0; j < 32; j += 8)
    tile[ty + j][tx] = in[(size_t)(by + ty + j) * C + bx + tx];
  __syncthreads();
#pragma unroll
  for (int j = 0; j < 32; j += 8)
    out[(size_t)(bx + ty + j) * R + by + tx] = f32_to_bf16_bits(tile[tx][ty + j]);
}

// ---------------------------------------------------------------- GEMM
// 256x256 tile, BK=64, 8 waves (2M x 4N), m201-style FINE-GRAINED 4-phase
// schedule: reads per phase {8,4,8,4} (small batches so the CU-wide DS FIFO
// drains each wave's reads quickly and wave-stagger overlaps MFMA with other
// waves' reads); exactly 1 half-tile DMA stage per phase in region-freed
// order; lgkmcnt(0) per phase; vmcnt(6) ONCE per tile at P4 (drains tile
// kt+1 fully, leaves kt+2's 3 staged halves in flight); setprio around MFMA.
// B-pair0 prefetched at P4 post-vmcnt-barrier into ping-pong bvA/bvB.
template <bool OUT_BF16>
__global__ __launch_bounds__(512, 1) void gemm_bt(
    const unsigned short* __restrict__ A,
    const unsigned short* __restrict__ BT,
    unsigned short* __restrict__ Cb,
    float* __restrict__ Cf,
    const float* __restrict__ bias,
    int M, int N) {
  constexpr int K = 2048;
  constexpr int BK = 64;
  constexpr int NKT = K / BK;          // 32
  __shared__ __align__(16) char lds[131072];  // [2 bufs][A 32KB | B 32KB]

  const int nbx = N / 256;
  const int nwg = gridDim.x;           // % 8 == 0
  const int bid = blockIdx.x;
  const int swzb = (bid & 7) * (nwg >> 3) + (bid >> 3);
  const int by = swzb / nbx;
  const int bx = swzb % nbx;

  const int t    = threadIdx.x;
  const int lane = t & 63;
  const int wid  = t >> 6;             // 0..7
  const int wr   = wid >> 2;           // 0..1 (M)
  const int wc   = wid & 3;            // 0..3 (N)
  const int lr   = lane & 15;
  const int g    = lane >> 4;          // 0..3

  const unsigned short* aSrc = A  + (size_t)by * 256 * K;
  const unsigned short* bSrc = BT + (size_t)bx * 256 * K;

  // staging source offsets (inverse-swizzled global, linear LDS dest)
  int aoff[2], boff[2];
#pragma unroll
  for (int i = 0; i < 2; ++i) {
    const int p   = (i * 512 + t) * 16;
    const int lo  = p ^ (((p >> 7) & 7) << 4);
    const int rih = lo >> 7;
    const int kbe = (lo & 127) >> 1;
    aoff[i] = (((rih >> 6) << 7) + (rih & 63)) * K + kbe;
    boff[i] = (((rih >> 5) << 6) + (rih & 31)) * K + kbe;
  }
  const int ldst = wid << 10;

  auto stageA = [&](int h, int k0, char* bufA) {
#pragma unroll
    for (int i = 0; i < 2; ++i)
      GLOAD16(aSrc + aoff[i] + h * (64 * K) + k0, bufA + h * 16384 + i * 8192 + ldst);
  };
  auto stageB = [&](int h, int k0, char* bufB) {
#pragma unroll
    for (int i = 0; i < 2; ++i)
      GLOAD16(bSrc + boff[i] + h * (32 * K) + k0, bufB + h * 16384 + i * 8192 + ldst);
  };

  // swizzled ds_read addresses
  const int sw   = (lr & 7) << 4;
  const int col0 = (g * 16) ^ sw;
  const int col1 = (64 + g * 16) ^ sw;
  const int aRow = (wr * 64 + lr) * 128;
  const int bRow = (wc * 32 + lr) * 128;

  f32x4_t acc[8][4] = {};
  bf16x8_t av[4][2];                   // A quadrant frags [m2][ks] (reused q0/q1)
  bf16x8_t bvA[2][2], bvB[2][2];       // B pair0 frags, ping-pong per tile
  bf16x8_t bv1[2][2];                  // B pair1 frags

#define LDA_INTO(dst, bufA_, q)                                                \
  {                                                                            \
    const char* _b = (bufA_) + (q) * 16384 + aRow;                             \
    _Pragma("unroll") for (int m2 = 0; m2 < 4; ++m2) {                         \
      dst[m2][0] = *(const bf16x8_t*)(_b + m2 * 2048 + col0);                  \
      dst[m2][1] = *(const bf16x8_t*)(_b + m2 * 2048 + col1);                  \
    }                                                                          \
  }
#define LDB_INTO(dst, bufB_, pair)                                             \
  {                                                                            \
    _Pragma("unroll") for (int e = 0; e < 2; ++e) {                            \
      const int nf = (pair) * 2 + e;                                           \
      const char* _b = (bufB_) + (nf >> 1) * 16384 + (nf & 1) * 2048 + bRow;   \
      dst[e][0] = *(const bf16x8_t*)(_b + col0);                               \
      dst[e][1] = *(const bf16x8_t*)(_b + col1);                               \
    }                                                                          \
  }
#define MFMAQ(AV, BV, Q, PAIR)                                                 \
  _Pragma("unroll") for (int m2 = 0; m2 < 4; ++m2)                             \
  _Pragma("unroll") for (int e = 0; e < 2; ++e)                                \
  _Pragma("unroll") for (int ks = 0; ks < 2; ++ks)                             \
    acc[(Q) * 4 + m2][(PAIR) * 2 + e] = __builtin_amdgcn_mfma_f32_16x16x32_bf16( \
        AV[m2][ks], BV[e][ks], acc[(Q) * 4 + m2][(PAIR) * 2 + e], 0, 0, 0);

#define SBR __builtin_amdgcn_sched_barrier(0)
#define BARR __builtin_amdgcn_s_barrier()
#define LGKM0 asm volatile("s_waitcnt lgkmcnt(0)" ::: "memory"); SBR;
#define P1_ __builtin_amdgcn_s_setprio(1);
#define P0_ __builtin_amdgcn_s_setprio(0); SBR;

  // One K-tile, 4 fine phases. BVC = B-pair0 regs for THIS tile (read at
  // prev P4); BVN = pair0 regs for next tile (read this P4).
#define BODY(KT, BVC, BVN, S1, S2, VMN)                                        \
  {                                                                            \
    char* cA = lds + ((KT) & 1) * 65536;                                       \
    char* cB = cA + 32768;                                                     \
    char* nB = lds + (((KT) + 1) & 1) * 65536 + 32768;                         \
    const int k1 = ((KT) + 1) * BK, k2 = ((KT) + 2) * BK;                      \
    /* P1: read A0 (8); stage Bh0(kt+1)->nB; MFMA (A0 x pair0) */              \
    LDA_INTO(av, cA, 0); SBR;                                                  \
    if (S1) { stageB(0, k1, nB); } SBR;                                        \
    BARR; LGKM0; P1_;                                                          \
    MFMAQ(av, BVC, 0, 0);                                                      \
    P0_; BARR;                                                                 \
    /* P2: read B1 (4); stage Ah0(kt+2)->cA (region freed at P1); MFMA */      \
    LDB_INTO(bv1, cB, 1); SBR;                                                 \
    if (S2) { stageA(0, k2, cA); } SBR;                                        \
    BARR; LGKM0; P1_;                                                          \
    MFMAQ(av, bv1, 0, 1);                                                      \
    P0_; BARR;                                                                 \
    /* P3: read A1 (8, reuse av regs); stage Bh1(kt+2)->cB (freed P2) */       \
    LDA_INTO(av, cA, 1); SBR;                                                  \
    if (S2) { stageB(1, k2, cB); } SBR;                                        \
    BARR; LGKM0; P1_;                                                          \
    MFMAQ(av, bv1, 1, 1);                                                      \
    P0_; BARR;                                                                 \
    /* P4: stage Ah1(kt+2)->cA (freed P3); vmcnt (drains tile kt+1 fully);     \
       barrier; prefetch BVN <- B0(kt+1); MFMA (A1 x pair0) */                 \
    if (S2) { stageA(1, k2, cA); } SBR;                                        \
    asm volatile("s_waitcnt vmcnt(" #VMN ")" ::: "memory"); SBR;               \
    BARR;                                                                      \
    if (S1) { LDB_INTO(BVN, nB, 0); } SBR;                                     \
    P1_;                                                                       \
    MFMAQ(av, BVC, 1, 0);                                                      \
    P0_; BARR;                                                                 \
  }

  // ---- prologue: tile0 all 4 halves + tile1 {Ah0, Bh1, Ah1} (Bh0(1) is
  // staged at kt0 P1); vmcnt(6) = tile0 landed (tile1's 3 halves in flight);
  // barrier; pre-read bvA <- B0(tile0) (drains at kt0 P1's lgkm(0)).
  {
    char* b0A = lds;
    char* b0B = lds + 32768;
    char* b1A = lds + 65536;
    char* b1B = b1A + 32768;
    stageA(0, 0, b0A); stageA(1, 0, b0A);
    stageB(0, 0, b0B); stageB(1, 0, b0B);
    stageA(0, BK, b1A);
    stageB(1, BK, b1B);
    stageA(1, BK, b1A);
    asm volatile("s_waitcnt vmcnt(6)" ::: "memory");
    BARR;
    LDB_INTO(bvA, b0B, 0);
    SBR;
  }

  // steady: tiles 0..29 (even: pair0 in bvA; odd: in bvB); peel 30, 31.
  for (int kt = 0; kt < NKT - 2; kt += 2) {
    BODY(kt,     bvA, bvB, 1, 1, 6);
    BODY(kt + 1, bvB, bvA, 1, 1, 6);
  }
  BODY(NKT - 2, bvA, bvB, 1, 0, 0);
  BODY(NKT - 1, bvB, bvA, 0, 0, 0);

  // ---- epilogue: C/D map col=lane&15, row=(lane>>4)*4+j
  const int rbase = by * 256 + wr * 128 + g * 4;
  const int cbase = bx * 256 + wc * 64 + lr;
#pragma unroll
  for (int m = 0; m < 8; ++m) {
#pragma unroll
    for (int nf = 0; nf < 4; ++nf) {
      const int col = cbase + nf * 16;
#pragma unroll
      for (int j = 0; j < 4; ++j) {
        const size_t off = (size_t)(rbase + (m >> 2) * 64 + (m & 3) * 16 + j) * N + col;
        if constexpr (OUT_BF16) {
          Cb[off] = f32_to_bf16_bits(acc[m][nf][j]);
        } else {
          Cf[off] = acc[m][nf][j] + bias[col];
        }
      }
    }
  }
#undef LDA_INTO
#undef LDB_INTO
#undef MFMAQ
#undef SBR
#undef BARR
#undef LGKM0
#undef P1_
#undef P0_
#undef BODY
}

// ---------------------------------------------------------------- attention
__global__ __launch_bounds__(256) void attn_heads(
    const unsigned short* __restrict__ qkv,  // [T][6144] bf16
    unsigned short* __restrict__ attn) {     // [T][2048] bf16
  __shared__ __align__(16) unsigned short sQKV[NQKV];
  __shared__ float sW[16][16];

  const int t = threadIdx.x;
  const size_t qbase = (size_t)blockIdx.x * NQKV;

  const uint4* gp = (const uint4*)(qkv + qbase);
  uint4* l = (uint4*)sQKV;
#pragma unroll
  for (int i = 0; i < 3; ++i) {
    const int idx = i * 256 + t;
    int dst = idx;
    if (idx >= 256 && idx < 512) {
      const int r = (idx - 256) >> 4;
      const int c = idx & 15;
      dst = 256 + r * 16 + (c ^ (r & 7));
    }
    l[dst] = gp[idx];
  }
  __syncthreads();

  const int h = t >> 4;
  const int H = t & 15;
  const bf16x8_t* q8 = (const bf16x8_t*)sQKV + h * 16;
  const bf16x8_t* k8 = (const bf16x8_t*)sQKV + 256;
  float s = 0.f;
#pragma unroll
  for (int d8 = 0; d8 < 16; ++d8) {
    bf16x8_t qv = q8[d8];
    bf16x8_t kv = k8[H * 16 + (d8 ^ (H & 7))];
#pragma unroll
    for (int j = 0; j < 8; ++j)
      s = fmaf((float)qv[j], (float)kv[j], s);
  }
  s *= 0.08838834764831843f;

  float mx = s;
#pragma unroll
  for (int o = 8; o; o >>= 1) mx = fmaxf(mx, __shfl_xor(mx, o));
  const float e = __expf(s - mx);
  float sum = e;
#pragma unroll
  for (int o = 8; o; o >>= 1) sum += __shfl_xor(sum, o);
  sW[h][H] = e / sum;
  __syncthreads();

  const int d0c = t & 15;
  const bf16x8_t* v8 = (const bf16x8_t*)sQKV + 512;
  float accv[8] = {};
#pragma unroll
  for (int j = 0; j < 16; ++j) {
    const float w = sW[h][j];
    const bf16x8_t vv = v8[j * 16 + d0c];
#pragma unroll
    for (int jj = 0; jj < 8; ++jj)
      accv[jj] = fmaf(w, (float)vv[jj], accv[jj]);
  }
  bf16x8_t o;
#pragma unroll
  for (int jj = 0; jj < 8; ++jj) o[jj] = (__bf16)accv[jj];
  *(bf16x8_t*)(attn + (size_t)blockIdx.x * EMB + h * 128 + d0c * 8) = o;
}

// ---------------------------------------------------------------- launch
extern "C" void kernel_launch(void* const* d_in, const int* in_sizes, int n_in,
                              void* d_out, int out_size, void* d_ws, size_t ws_size,
                              hipStream_t stream) {
  const float* x    = (const float*)d_in[0];
  const float* Wqkv = (const float*)d_in[1];
  const float* Wout = (const float*)d_in[2];
  const float* bout = (const float*)d_in[3];
  float* out = (float*)d_out;

  unsigned short* xb    = (unsigned short*)d_ws;          // 33,554,432
  unsigned short* wqkvT = xb    + (size_t)33554432;       // 12,582,912
  unsigned short* woutT = wqkvT + (size_t)12582912;       //  4,194,304
  unsigned short* qkv   = woutT + (size_t)4194304;        // 100,663,296
  unsigned short* attn  = qkv   + (size_t)100663296;      // 33,554,432

  cvt_f32_bf16<<<2048, 256, 0, stream>>>((const float4*)x, (ushort4*)xb, 33554432 / 4);
  transpose_cvt<<<dim3(6144 / 32, 2048 / 32), dim3(32, 8), 0, stream>>>(Wqkv, wqkvT, 2048, 6144);
  transpose_cvt<<<dim3(2048 / 32, 2048 / 32), dim3(32, 8), 0, stream>>>(Wout, woutT, 2048, 2048);
  // qkv = x @ W_qkv : grid 64*24 = 1536 (%8==0)
  gemm_bt<true><<<(16384 / 256) * (6144 / 256), 512, 0, stream>>>(
      xb, wqkvT, qkv, nullptr, nullptr, 16384, 6144);
  attn_heads<<<TOKENS, 256, 0, stream>>>(qkv, attn);
  // out = attn @ W_out + b_out : grid 64*8 = 512 (%8==0)
  gemm_bt<false><<<(16384 / 256) * (2048 / 256), 512, 0, stream>>>(
      attn, woutT, nullptr, out, bout, 16384, 2048);
}

// Round 13
// 609.932 us; speedup vs baseline: 1.1900x; 1.0044x over previous
//
#include <hip/hip_runtime.h>
#include <hip/hip_bf16.h>
#include <cstdint>

// B=4, S=4096, E=2048, H=16, D=128 -> 16384 independent tokens.
// qkv = x @ W_qkv (16384x2048x6144); per-token 16x16 head mix;
// out = attn @ W_out + b_out (16384x2048x2048).

#define TOKENS 16384
#define EMB    2048
#define NQKV   6144

typedef __bf16 bf16x8_t __attribute__((ext_vector_type(8)));
typedef float  f32x4_t  __attribute__((ext_vector_type(4)));

#define GLOAD16(gsrc, ldst)                                                    \
  __builtin_amdgcn_global_load_lds(                                            \
      (const __attribute__((address_space(1))) void*)(uintptr_t)(gsrc),        \
      (__attribute__((address_space(3))) void*)(uint32_t)(uintptr_t)(ldst),    \
      16, 0, 0)

static __device__ __forceinline__ unsigned short f32_to_bf16_bits(float f) {
  union { float f; uint32_t u; } x; x.f = f;
  uint32_t u = x.u;
  u += 0x7fffu + ((u >> 16) & 1u);   // round-to-nearest-even
  return (unsigned short)(u >> 16);
}

// ------------------------------------------------- merged prep kernel
// blocks [0,2048): x f32 -> bf16 (grid-stride over 8M float4)
// blocks [2048,14336): W_qkv transpose-cvt (192 x 64 tile grid)
// blocks [14336,18432): W_out transpose-cvt (64 x 64 tile grid)
__global__ __launch_bounds__(256) void prep(
    const float4* __restrict__ x4, ushort4* __restrict__ xb4,
    const float* __restrict__ Wqkv, unsigned short* __restrict__ wqkvT,
    const float* __restrict__ Wout, unsigned short* __restrict__ woutT) {
  const int b = blockIdx.x;
  const int t = threadIdx.x;
  if (b < 2048) {
    const int n4 = 33554432 / 4;
    const int stride = 2048 * 256;
    for (int i = b * 256 + t; i < n4; i += stride) {
      float4 v = x4[i];
      ushort4 o;
      o.x = f32_to_bf16_bits(v.x);
      o.y = f32_to_bf16_bits(v.y);
      o.z = f32_to_bf16_bits(v.z);
      o.w = f32_to_bf16_bits(v.w);
      xb4[i] = o;
    }
    return;
  }
  __shared__ float tile[32][33];
  const float* in;
  unsigned short* out;
  int R, C, bxt, byt;
  if (b < 14336) {
    const int bb = b - 2048;
    in = Wqkv; out = wqkvT; R = 2048; C = 6144;
    bxt = bb % 192; byt = bb / 192;
  } else {
    const int bb = b - 14336;
    in = Wout; out = woutT; R = 2048; C = 2048;
    bxt = bb % 64; byt = bb / 64;
  }
  const int bx = bxt * 32;
  const int by = byt * 32;
  const int tx = t & 31;
  const int ty = t >> 5;   // 0..7
#pragma unroll
  for (int j = 0; j < 32; j += 8)
    tile[ty + j][tx] = in[(size_t)(by + ty + j) * C + bx + tx];
  __syncthreads();
#pragma unroll
  for (int j = 0; j < 32; j += 8)
    out[(size_t)(bx + ty + j) * R + by + tx] = f32_to_bf16_bits(tile[tx][ty + j]);
}

// ---------------------------------------------------------------- GEMM
// 256x256 tile, BK=64, 8 waves (2M x 4N), R12 fine 4-phase skeleton +
// INTRA-PHASE lgkm SPLITS: each phase waits only for the first half of its
// ds_reads (lgkmcnt(4)/(2)), runs 8 MFMA while the rest drain, then
// lgkmcnt(0) + the other 8. P4 needs no lgkm wait (operands long-drained);
// its BVN prefetch rides into next P1's lgkm(4). Barriers/stages/vmcnt and
// registers byte-identical to R12 (race coverage preserved).
template <bool OUT_BF16>
__global__ __launch_bounds__(512, 1) void gemm_bt(
    const unsigned short* __restrict__ A,
    const unsigned short* __restrict__ BT,
    unsigned short* __restrict__ Cb,
    float* __restrict__ Cf,
    const float* __restrict__ bias,
    int M, int N) {
  constexpr int K = 2048;
  constexpr int BK = 64;
  constexpr int NKT = K / BK;          // 32
  __shared__ __align__(16) char lds[131072];  // [2 bufs][A 32KB | B 32KB]

  const int nbx = N / 256;
  const int nwg = gridDim.x;           // % 8 == 0
  const int bid = blockIdx.x;
  const int swzb = (bid & 7) * (nwg >> 3) + (bid >> 3);
  const int by = swzb / nbx;
  const int bx = swzb % nbx;

  const int t    = threadIdx.x;
  const int lane = t & 63;
  const int wid  = t >> 6;             // 0..7
  const int wr   = wid >> 2;           // 0..1 (M)
  const int wc   = wid & 3;            // 0..3 (N)
  const int lr   = lane & 15;
  const int g    = lane >> 4;          // 0..3

  const unsigned short* aSrc = A  + (size_t)by * 256 * K;
  const unsigned short* bSrc = BT + (size_t)bx * 256 * K;

  // staging source offsets (inverse-swizzled global, linear LDS dest)
  int aoff[2], boff[2];
#pragma unroll
  for (int i = 0; i < 2; ++i) {
    const int p   = (i * 512 + t) * 16;
    const int lo  = p ^ (((p >> 7) & 7) << 4);
    const int rih = lo >> 7;
    const int kbe = (lo & 127) >> 1;
    aoff[i] = (((rih >> 6) << 7) + (rih & 63)) * K + kbe;
    boff[i] = (((rih >> 5) << 6) + (rih & 31)) * K + kbe;
  }
  const int ldst = wid << 10;

  auto stageA = [&](int h, int k0, char* bufA) {
#pragma unroll
    for (int i = 0; i < 2; ++i)
      GLOAD16(aSrc + aoff[i] + h * (64 * K) + k0, bufA + h * 16384 + i * 8192 + ldst);
  };
  auto stageB = [&](int h, int k0, char* bufB) {
#pragma unroll
    for (int i = 0; i < 2; ++i)
      GLOAD16(bSrc + boff[i] + h * (32 * K) + k0, bufB + h * 16384 + i * 8192 + ldst);
  };

  // swizzled ds_read addresses
  const int sw   = (lr & 7) << 4;
  const int col0 = (g * 16) ^ sw;
  const int col1 = (64 + g * 16) ^ sw;
  const int aRow = (wr * 64 + lr) * 128;
  const int bRow = (wc * 32 + lr) * 128;

  f32x4_t acc[8][4] = {};
  bf16x8_t av[4][2];                   // A quadrant frags [m2][ks] (reused q0/q1)
  bf16x8_t bvA[2][2], bvB[2][2];       // B pair0 frags, ping-pong per tile
  bf16x8_t bv1[2][2];                  // B pair1 frags

#define LDA_INTO(dst, bufA_, q)                                                \
  {                                                                            \
    const char* _b = (bufA_) + (q) * 16384 + aRow;                             \
    _Pragma("unroll") for (int m2 = 0; m2 < 4; ++m2) {                         \
      dst[m2][0] = *(const bf16x8_t*)(_b + m2 * 2048 + col0);                  \
      dst[m2][1] = *(const bf16x8_t*)(_b + m2 * 2048 + col1);                  \
    }                                                                          \
  }
#define LDB_INTO(dst, bufB_, pair)                                             \
  {                                                                            \
    _Pragma("unroll") for (int e = 0; e < 2; ++e) {                            \
      const int nf = (pair) * 2 + e;                                           \
      const char* _b = (bufB_) + (nf >> 1) * 16384 + (nf & 1) * 2048 + bRow;   \
      dst[e][0] = *(const bf16x8_t*)(_b + col0);                               \
      dst[e][1] = *(const bf16x8_t*)(_b + col1);                               \
    }                                                                          \
  }
#define MFMAQ(AV, BV, Q, PAIR)                                                 \
  _Pragma("unroll") for (int m2 = 0; m2 < 4; ++m2)                             \
  _Pragma("unroll") for (int e = 0; e < 2; ++e)                                \
  _Pragma("unroll") for (int ks = 0; ks < 2; ++ks)                             \
    acc[(Q) * 4 + m2][(PAIR) * 2 + e] = __builtin_amdgcn_mfma_f32_16x16x32_bf16( \
        AV[m2][ks], BV[e][ks], acc[(Q) * 4 + m2][(PAIR) * 2 + e], 0, 0, 0);
  // half batches: by A-rows (M0..M0+1) or by B-column pair element (E)
#define MFMAQ_M(AV, BV, Q, PAIR, M0)                                           \
  _Pragma("unroll") for (int m2 = (M0); m2 < (M0) + 2; ++m2)                   \
  _Pragma("unroll") for (int e = 0; e < 2; ++e)                                \
  _Pragma("unroll") for (int ks = 0; ks < 2; ++ks)                             \
    acc[(Q) * 4 + m2][(PAIR) * 2 + e] = __builtin_amdgcn_mfma_f32_16x16x32_bf16( \
        AV[m2][ks], BV[e][ks], acc[(Q) * 4 + m2][(PAIR) * 2 + e], 0, 0, 0);
#define MFMAQ_E(AV, BV, Q, PAIR, E)                                            \
  _Pragma("unroll") for (int m2 = 0; m2 < 4; ++m2)                             \
  _Pragma("unroll") for (int ks = 0; ks < 2; ++ks)                             \
    acc[(Q) * 4 + m2][(PAIR) * 2 + (E)] = __builtin_amdgcn_mfma_f32_16x16x32_bf16( \
        AV[m2][ks], BV[(E)][ks], acc[(Q) * 4 + m2][(PAIR) * 2 + (E)], 0, 0, 0);

#define SBR __builtin_amdgcn_sched_barrier(0)
#define BARR __builtin_amdgcn_s_barrier()
#define LGKM(NN) asm volatile("s_waitcnt lgkmcnt(" #NN ")" ::: "memory"); SBR;
#define P1_ __builtin_amdgcn_s_setprio(1);
#define P0_ __builtin_amdgcn_s_setprio(0); SBR;

  // One K-tile, 4 fine phases with intra-phase lgkm splits.
#define BODY(KT, BVC, BVN, S1, S2, VMN)                                        \
  {                                                                            \
    char* cA = lds + ((KT) & 1) * 65536;                                       \
    char* cB = cA + 32768;                                                     \
    char* nB = lds + (((KT) + 1) & 1) * 65536 + 32768;                         \
    const int k1 = ((KT) + 1) * BK, k2 = ((KT) + 2) * BK;                      \
    /* P1: read A0 (8); stage Bh0(kt+1); lgkm(4) -> av[0..1]+BVC ready;        \
       8 MFMA while r4-7 drain; lgkm(0); 8 MFMA */                             \
    LDA_INTO(av, cA, 0); SBR;                                                  \
    if (S1) { stageB(0, k1, nB); } SBR;                                        \
    BARR; LGKM(4); P1_;                                                        \
    MFMAQ_M(av, BVC, 0, 0, 0);                                                 \
    LGKM(0);                                                                   \
    MFMAQ_M(av, BVC, 0, 0, 2);                                                 \
    P0_; BARR;                                                                 \
    /* P2: read B1 (4); stage Ah0(kt+2); lgkm(2) -> bv1[0]; 8 MFMA; lgkm(0);   \
       8 MFMA */                                                               \
    LDB_INTO(bv1, cB, 1); SBR;                                                 \
    if (S2) { stageA(0, k2, cA); } SBR;                                        \
    BARR; LGKM(2); P1_;                                                        \
    MFMAQ_E(av, bv1, 0, 1, 0);                                                 \
    LGKM(0);                                                                   \
    MFMAQ_E(av, bv1, 0, 1, 1);                                                 \
    P0_; BARR;                                                                 \
    /* P3: read A1 (8, reuse av); stage Bh1(kt+2); split as P1 */              \
    LDA_INTO(av, cA, 1); SBR;                                                  \
    if (S2) { stageB(1, k2, cB); } SBR;                                        \
    BARR; LGKM(4); P1_;                                                        \
    MFMAQ_M(av, bv1, 1, 1, 0);                                                 \
    LGKM(0);                                                                   \
    MFMAQ_M(av, bv1, 1, 1, 2);                                                 \
    P0_; BARR;                                                                 \
    /* P4: stage Ah1(kt+2); vmcnt; barrier; prefetch BVN (rides into next      \
       P1's lgkm(4)); 16 MFMA with NO lgkm wait (operands long-drained) */     \
    if (S2) { stageA(1, k2, cA); } SBR;                                        \
    asm volatile("s_waitcnt vmcnt(" #VMN ")" ::: "memory"); SBR;               \
    BARR;                                                                      \
    if (S1) { LDB_INTO(BVN, nB, 0); } SBR;                                     \
    P1_;                                                                       \
    MFMAQ(av, BVC, 1, 0);                                                      \
    P0_; BARR;                                                                 \
  }

  // ---- prologue: tile0 all 4 halves + tile1 {Ah0, Bh1, Ah1} (Bh0(1) staged
  // at kt0 P1); vmcnt(6) = tile0 landed; barrier; pre-read bvA <- B0(tile0).
  {
    char* b0A = lds;
    char* b0B = lds + 32768;
    char* b1A = lds + 65536;
    char* b1B = b1A + 32768;
    stageA(0, 0, b0A); stageA(1, 0, b0A);
    stageB(0, 0, b0B); stageB(1, 0, b0B);
    stageA(0, BK, b1A);
    stageB(1, BK, b1B);
    stageA(1, BK, b1A);
    asm volatile("s_waitcnt vmcnt(6)" ::: "memory");
    BARR;
    LDB_INTO(bvA, b0B, 0);
    SBR;
  }

  // steady: tiles 0..29 (even: pair0 in bvA; odd: in bvB); peel 30, 31.
  for (int kt = 0; kt < NKT - 2; kt += 2) {
    BODY(kt,     bvA, bvB, 1, 1, 6);
    BODY(kt + 1, bvB, bvA, 1, 1, 6);
  }
  BODY(NKT - 2, bvA, bvB, 1, 0, 0);
  BODY(NKT - 1, bvB, bvA, 0, 0, 0);

  // ---- epilogue: C/D map col=lane&15, row=(lane>>4)*4+j
  const int rbase = by * 256 + wr * 128 + g * 4;
  const int cbase = bx * 256 + wc * 64 + lr;
#pragma unroll
  for (int m = 0; m < 8; ++m) {
#pragma unroll
    for (int nf = 0; nf < 4; ++nf) {
      const int col = cbase + nf * 16;
#pragma unroll
      for (int j = 0; j < 4; ++j) {
        const size_t off = (size_t)(rbase + (m >> 2) * 64 + (m & 3) * 16 + j) * N + col;
        if constexpr (OUT_BF16) {
          Cb[off] = f32_to_bf16_bits(acc[m][nf][j]);
        } else {
          Cf[off] = acc[m][nf][j] + bias[col];
        }
      }
    }
  }
#undef LDA_INTO
#undef LDB_INTO
#undef MFMAQ
#undef MFMAQ_M
#undef MFMAQ_E
#undef SBR
#undef BARR
#undef LGKM
#undef P1_
#undef P0_
#undef BODY
}

// ---------------------------------------------------------------- attention
__global__ __launch_bounds__(256) void attn_heads(
    const unsigned short* __restrict__ qkv,  // [T][6144] bf16
    unsigned short* __restrict__ attn) {     // [T][2048] bf16
  __shared__ __align__(16) unsigned short sQKV[NQKV];
  __shared__ float sW[16][16];

  const int t = threadIdx.x;
  const size_t qbase = (size_t)blockIdx.x * NQKV;

  const uint4* gp = (const uint4*)(qkv + qbase);
  uint4* l = (uint4*)sQKV;
#pragma unroll
  for (int i = 0; i < 3; ++i) {
    const int idx = i * 256 + t;
    int dst = idx;
    if (idx >= 256 && idx < 512) {
      const int r = (idx - 256) >> 4;
      const int c = idx & 15;
      dst = 256 + r * 16 + (c ^ (r & 7));
    }
    l[dst] = gp[idx];
  }
  __syncthreads();

  const int h = t >> 4;
  const int H = t & 15;
  const bf16x8_t* q8 = (const bf16x8_t*)sQKV + h * 16;
  const bf16x8_t* k8 = (const bf16x8_t*)sQKV + 256;
  float s = 0.f;
#pragma unroll
  for (int d8 = 0; d8 < 16; ++d8) {
    bf16x8_t qv = q8[d8];
    bf16x8_t kv = k8[H * 16 + (d8 ^ (H & 7))];
#pragma unroll
    for (int j = 0; j < 8; ++j)
      s = fmaf((float)qv[j], (float)kv[j], s);
  }
  s *= 0.08838834764831843f;

  float mx = s;
#pragma unroll
  for (int o = 8; o; o >>= 1) mx = fmaxf(mx, __shfl_xor(mx, o));
  const float e = __expf(s - mx);
  float sum = e;
#pragma unroll
  for (int o = 8; o; o >>= 1) sum += __shfl_xor(sum, o);
  sW[h][H] = e / sum;
  __syncthreads();

  const int d0c = t & 15;
  const bf16x8_t* v8 = (const bf16x8_t*)sQKV + 512;
  float accv[8] = {};
#pragma unroll
  for (int j = 0; j < 16; ++j) {
    const float w = sW[h][j];
    const bf16x8_t vv = v8[j * 16 + d0c];
#pragma unroll
    for (int jj = 0; jj < 8; ++jj)
      accv[jj] = fmaf(w, (float)vv[jj], accv[jj]);
  }
  bf16x8_t o;
#pragma unroll
  for (int jj = 0; jj < 8; ++jj) o[jj] = (__bf16)accv[jj];
  *(bf16x8_t*)(attn + (size_t)blockIdx.x * EMB + h * 128 + d0c * 8) = o;
}

// ---------------------------------------------------------------- launch
extern "C" void kernel_launch(void* const* d_in, const int* in_sizes, int n_in,
                              void* d_out, int out_size, void* d_ws, size_t ws_size,
                              hipStream_t stream) {
  const float* x    = (const float*)d_in[0];
  const float* Wqkv = (const float*)d_in[1];
  const float* Wout = (const float*)d_in[2];
  const float* bout = (const float*)d_in[3];
  float* out = (float*)d_out;

  unsigned short* xb    = (unsigned short*)d_ws;          // 33,554,432
  unsigned short* wqkvT = xb    + (size_t)33554432;       // 12,582,912
  unsigned short* woutT = wqkvT + (size_t)12582912;       //  4,194,304
  unsigned short* qkv   = woutT + (size_t)4194304;        // 100,663,296
  unsigned short* attn  = qkv   + (size_t)100663296;      // 33,554,432

  // merged prep: x->bf16 + W_qkv^T + W_out^T in one launch
  prep<<<18432, 256, 0, stream>>>((const float4*)x, (ushort4*)xb,
                                  Wqkv, wqkvT, Wout, woutT);
  // qkv = x @ W_qkv : grid 64*24 = 1536 (%8==0)
  gemm_bt<true><<<(16384 / 256) * (6144 / 256), 512, 0, stream>>>(
      xb, wqkvT, qkv, nullptr, nullptr, 16384, 6144);
  attn_heads<<<TOKENS, 256, 0, stream>>>(qkv, attn);
  // out = attn @ W_out + b_out : grid 64*8 = 512 (%8==0)
  gemm_bt<false><<<(16384 / 256) * (2048 / 256), 512, 0, stream>>>(
      attn, woutT, nullptr, out, bout, 16384, 2048);
}

// Round 14
// 598.239 us; speedup vs baseline: 1.2133x; 1.0195x over previous
//
#include <hip/hip_runtime.h>
#include <hip/hip_bf16.h>
#include <cstdint>

// B=4, S=4096, E=2048, H=16, D=128 -> 16384 independent tokens.
// qkv = x @ W_qkv (16384x2048x6144); per-token 16x16 head mix;
// out = attn @ W_out + b_out (16384x2048x2048).

#define TOKENS 16384
#define EMB    2048
#define NQKV   6144

typedef __bf16 bf16x8_t __attribute__((ext_vector_type(8)));
typedef float  f32x4_t  __attribute__((ext_vector_type(4)));

#define GLOAD16(gsrc, ldst)                                                    \
  __builtin_amdgcn_global_load_lds(                                            \
      (const __attribute__((address_space(1))) void*)(uintptr_t)(gsrc),        \
      (__attribute__((address_space(3))) void*)(uint32_t)(uintptr_t)(ldst),    \
      16, 0, 0)

static __device__ __forceinline__ unsigned short f32_to_bf16_bits(float f) {
  union { float f; uint32_t u; } x; x.f = f;
  uint32_t u = x.u;
  u += 0x7fffu + ((u >> 16) & 1u);   // round-to-nearest-even
  return (unsigned short)(u >> 16);
}

// ------------------------------------------------- merged prep kernel
__global__ __launch_bounds__(256) void prep(
    const float4* __restrict__ x4, ushort4* __restrict__ xb4,
    const float* __restrict__ Wqkv, unsigned short* __restrict__ wqkvT,
    const float* __restrict__ Wout, unsigned short* __restrict__ woutT) {
  const int b = blockIdx.x;
  const int t = threadIdx.x;
  if (b < 2048) {
    const int n4 = 33554432 / 4;
    const int stride = 2048 * 256;
    for (int i = b * 256 + t; i < n4; i += stride) {
      float4 v = x4[i];
      ushort4 o;
      o.x = f32_to_bf16_bits(v.x);
      o.y = f32_to_bf16_bits(v.y);
      o.z = f32_to_bf16_bits(v.z);
      o.w = f32_to_bf16_bits(v.w);
      xb4[i] = o;
    }
    return;
  }
  __shared__ float tile[32][33];
  const float* in;
  unsigned short* out;
  int R, C, bxt, byt;
  if (b < 14336) {
    const int bb = b - 2048;
    in = Wqkv; out = wqkvT; R = 2048; C = 6144;
    bxt = bb % 192; byt = bb / 192;
  } else {
    const int bb = b - 14336;
    in = Wout; out = woutT; R = 2048; C = 2048;
    bxt = bb % 64; byt = bb / 64;
  }
  const int bx = bxt * 32;
  const int by = byt * 32;
  const int tx = t & 31;
  const int ty = t >> 5;   // 0..7
#pragma unroll
  for (int j = 0; j < 32; j += 8)
    tile[ty + j][tx] = in[(size_t)(by + ty + j) * C + bx + tx];
  __syncthreads();
#pragma unroll
  for (int j = 0; j < 32; j += 8)
    out[(size_t)(bx + ty + j) * R + by + tx] = f32_to_bf16_bits(tile[tx][ty + j]);
}

// ---------------------------------------------------------------- GEMM
// 256x256 tile, BK=64, 8 waves (2M x 4N), WAVE-GROUP ROLE STAGGER:
// G0 = waves 0-3 (wr=0, rows 0-127), G1 = waves 4-7 (wr=1) -- one per SIMD.
// 4 slots/K-tile; in each slot one group ISSUES ds_reads while the other
// runs a 32-MFMA half (DS pipe and MFMA pipe concurrently busy):
//   s1: G0 R1{av q0, bv0, bv1} | G1 M_q1(kt-1);   stage Ah0(kt+1)
//   s2: G1 R1                  | G0 M_q0(kt);     stage Ah1(kt+1)
//   s3: G0 R2{av q1}           | G1 M_q0(kt)
//   s4: G1 R2                  | G0 M_q1(kt);     stage B(kt+2); vmcnt(4)
// Ah0/Ah1 stage-halves == G0/G1's private rows -> every overwrite is
// covered by (readers' lgkm drain -> barrier); vmcnt(4)@s4 drains exactly
// tile kt+1 (FIFO-verified incl. prologue). All lgkm waits are wave-local
// lgkmcnt(0) over reads issued one slot earlier (DS work hides under the
// other group's MFMA). av reused q0->q1 (64 frag VGPR + 128 acc).
template <bool OUT_BF16>
__global__ __launch_bounds__(512, 1) void gemm_bt(
    const unsigned short* __restrict__ A,
    const unsigned short* __restrict__ BT,
    unsigned short* __restrict__ Cb,
    float* __restrict__ Cf,
    const float* __restrict__ bias,
    int M, int N) {
  constexpr int K = 2048;
  constexpr int BK = 64;
  constexpr int NKT = K / BK;          // 32
  __shared__ __align__(16) char lds[131072];  // [2 bufs][A 32KB | B 32KB]

  const int nbx = N / 256;
  const int nwg = gridDim.x;           // % 8 == 0
  const int bid = blockIdx.x;
  const int swzb = (bid & 7) * (nwg >> 3) + (bid >> 3);
  const int by = swzb / nbx;
  const int bx = swzb % nbx;

  const int t    = threadIdx.x;
  const int lane = t & 63;
  const int wid  = t >> 6;             // 0..7
  const int wr   = wid >> 2;           // 0..1 (M)  -> group id
  const int wc   = wid & 3;            // 0..3 (N)
  const int lr   = lane & 15;
  const int g    = lane >> 4;          // 0..3
  const bool g0  = (wr == 0);

  const unsigned short* aSrc = A  + (size_t)by * 256 * K;
  const unsigned short* bSrc = BT + (size_t)bx * 256 * K;

  // staging source offsets (inverse-swizzled global, linear LDS dest)
  int aoff[2], boff[2];
#pragma unroll
  for (int i = 0; i < 2; ++i) {
    const int p   = (i * 512 + t) * 16;
    const int lo  = p ^ (((p >> 7) & 7) << 4);
    const int rih = lo >> 7;
    const int kbe = (lo & 127) >> 1;
    aoff[i] = (((rih >> 6) << 7) + (rih & 63)) * K + kbe;
    boff[i] = (((rih >> 5) << 6) + (rih & 31)) * K + kbe;
  }
  const int ldst = wid << 10;

  auto stageA = [&](int h, int k0, char* bufA) {
#pragma unroll
    for (int i = 0; i < 2; ++i)
      GLOAD16(aSrc + aoff[i] + h * (64 * K) + k0, bufA + h * 16384 + i * 8192 + ldst);
  };
  auto stageB = [&](int h, int k0, char* bufB) {
#pragma unroll
    for (int i = 0; i < 2; ++i)
      GLOAD16(bSrc + boff[i] + h * (32 * K) + k0, bufB + h * 16384 + i * 8192 + ldst);
  };

  // swizzled ds_read addresses
  const int sw   = (lr & 7) << 4;
  const int col0 = (g * 16) ^ sw;
  const int col1 = (64 + g * 16) ^ sw;
  const int aRow = (wr * 64 + lr) * 128;
  const int bRow = (wc * 32 + lr) * 128;

  f32x4_t acc[8][4] = {};
  bf16x8_t av[4][2];                   // A quadrant frags [m2][ks], reused q0/q1
  bf16x8_t bv0[2][2], bv1[2][2];       // B pair frags [e][ks]

#define LDA_INTO(dst, bufA_, q)                                                \
  {                                                                            \
    const char* _b = (bufA_) + (q) * 16384 + aRow;                             \
    _Pragma("unroll") for (int m2 = 0; m2 < 4; ++m2) {                         \
      dst[m2][0] = *(const bf16x8_t*)(_b + m2 * 2048 + col0);                  \
      dst[m2][1] = *(const bf16x8_t*)(_b + m2 * 2048 + col1);                  \
    }                                                                          \
  }
#define LDB_INTO(dst, bufB_, pair)                                             \
  {                                                                            \
    _Pragma("unroll") for (int e = 0; e < 2; ++e) {                            \
      const int nf = (pair) * 2 + e;                                           \
      const char* _b = (bufB_) + (nf >> 1) * 16384 + (nf & 1) * 2048 + bRow;   \
      dst[e][0] = *(const bf16x8_t*)(_b + col0);                               \
      dst[e][1] = *(const bf16x8_t*)(_b + col1);                               \
    }                                                                          \
  }
#define MFMAQ(AV, BV, Q, PAIR)                                                 \
  _Pragma("unroll") for (int m2 = 0; m2 < 4; ++m2)                             \
  _Pragma("unroll") for (int e = 0; e < 2; ++e)                                \
  _Pragma("unroll") for (int ks = 0; ks < 2; ++ks)                             \
    acc[(Q) * 4 + m2][(PAIR) * 2 + e] = __builtin_amdgcn_mfma_f32_16x16x32_bf16( \
        AV[m2][ks], BV[e][ks], acc[(Q) * 4 + m2][(PAIR) * 2 + e], 0, 0, 0);

#define SBR __builtin_amdgcn_sched_barrier(0)
#define BARR __builtin_amdgcn_s_barrier()
#define LGKM0 asm volatile("s_waitcnt lgkmcnt(0)" ::: "memory"); SBR;
#define P1_ __builtin_amdgcn_s_setprio(1);
#define P0_ __builtin_amdgcn_s_setprio(0); SBR;

  // MFMA halves by A-quadrant: M_q0 uses av(q0)+bv0+bv1; M_q1 uses av(q1).
#define MQ0 { LGKM0; P1_; MFMAQ(av, bv0, 0, 0); MFMAQ(av, bv1, 0, 1); P0_; }
#define MQ1 { LGKM0; P1_; MFMAQ(av, bv0, 1, 0); MFMAQ(av, bv1, 1, 1); P0_; }

#define BODY(KT, SA1, SB2, VMN, MP)                                            \
  {                                                                            \
    char* cA = lds + ((KT) & 1) * 65536;                                       \
    char* cB = cA + 32768;                                                     \
    char* nA = lds + (((KT) + 1) & 1) * 65536;                                 \
    const int k1 = ((KT) + 1) * BK, k2 = ((KT) + 2) * BK;                      \
    /* s1: G0 issue R1(kt); G1 finish M_q1(kt-1); stage Ah0(kt+1) */           \
    if (g0) { LDA_INTO(av, cA, 0); LDB_INTO(bv0, cB, 0); LDB_INTO(bv1, cB, 1); } \
    SBR;                                                                       \
    if (SA1) { stageA(0, k1, nA); } SBR;                                       \
    if (!g0 && (MP)) MQ1;                                                      \
    SBR; BARR;                                                                 \
    /* s2: G1 issue R1(kt); G0 M_q0(kt); stage Ah1(kt+1) */                    \
    if (!g0) { LDA_INTO(av, cA, 0); LDB_INTO(bv0, cB, 0); LDB_INTO(bv1, cB, 1); } \
    SBR;                                                                       \
    if (SA1) { stageA(1, k1, nA); } SBR;                                       \
    if (g0) MQ0;                                                               \
    SBR; BARR;                                                                 \
    /* s3: G0 issue R2(kt); G1 M_q0(kt) */                                     \
    if (g0) { LDA_INTO(av, cA, 1); } SBR;                                      \
    if (!g0) MQ0;                                                              \
    SBR; BARR;                                                                 \
    /* s4: G1 issue R2(kt); stage B(kt+2); vmcnt; G0 M_q1(kt) */               \
    if (!g0) { LDA_INTO(av, cA, 1); } SBR;                                     \
    if (SB2) { stageB(0, k2, cB); stageB(1, k2, cB); } SBR;                    \
    asm volatile("s_waitcnt vmcnt(" #VMN ")" ::: "memory"); SBR;               \
    if (g0) MQ1;                                                               \
    SBR; BARR;                                                                 \
  }

  // ---- prologue: B(0), Ah0(0), Ah1(0), B(1); vmcnt(4)=tile0 landed; barrier
  {
    char* b0A = lds;
    char* b0B = lds + 32768;
    char* b1B = lds + 65536 + 32768;
    stageB(0, 0, b0B); stageB(1, 0, b0B);
    stageA(0, 0, b0A);
    stageA(1, 0, b0A);
    stageB(0, BK, b1B); stageB(1, BK, b1B);
    asm volatile("s_waitcnt vmcnt(4)" ::: "memory");
    BARR;
  }

  BODY(0, 1, 1, 4, 0);
  for (int kt = 1; kt < NKT - 2; ++kt) {
    BODY(kt, 1, 1, 4, 1);
  }
  BODY(NKT - 2, 1, 0, 0, 1);
  BODY(NKT - 1, 0, 0, 0, 1);
  // trailing: G1's M_q1(NKT-1)
  if (!g0) MQ1;

  // ---- epilogue: C/D map col=lane&15, row=(lane>>4)*4+j
  const int rbase = by * 256 + wr * 128 + g * 4;
  const int cbase = bx * 256 + wc * 64 + lr;
#pragma unroll
  for (int m = 0; m < 8; ++m) {
#pragma unroll
    for (int nf = 0; nf < 4; ++nf) {
      const int col = cbase + nf * 16;
#pragma unroll
      for (int j = 0; j < 4; ++j) {
        const size_t off = (size_t)(rbase + (m >> 2) * 64 + (m & 3) * 16 + j) * N + col;
        if constexpr (OUT_BF16) {
          Cb[off] = f32_to_bf16_bits(acc[m][nf][j]);
        } else {
          Cf[off] = acc[m][nf][j] + bias[col];
        }
      }
    }
  }
#undef LDA_INTO
#undef LDB_INTO
#undef MFMAQ
#undef SBR
#undef BARR
#undef LGKM0
#undef P1_
#undef P0_
#undef MQ0
#undef MQ1
#undef BODY
}

// ---------------------------------------------------------------- attention
__global__ __launch_bounds__(256) void attn_heads(
    const unsigned short* __restrict__ qkv,  // [T][6144] bf16
    unsigned short* __restrict__ attn) {     // [T][2048] bf16
  __shared__ __align__(16) unsigned short sQKV[NQKV];
  __shared__ float sW[16][16];

  const int t = threadIdx.x;
  const size_t qbase = (size_t)blockIdx.x * NQKV;

  const uint4* gp = (const uint4*)(qkv + qbase);
  uint4* l = (uint4*)sQKV;
#pragma unroll
  for (int i = 0; i < 3; ++i) {
    const int idx = i * 256 + t;
    int dst = idx;
    if (idx >= 256 && idx < 512) {
      const int r = (idx - 256) >> 4;
      const int c = idx & 15;
      dst = 256 + r * 16 + (c ^ (r & 7));
    }
    l[dst] = gp[idx];
  }
  __syncthreads();

  const int h = t >> 4;
  const int H = t & 15;
  const bf16x8_t* q8 = (const bf16x8_t*)sQKV + h * 16;
  const bf16x8_t* k8 = (const bf16x8_t*)sQKV + 256;
  float s = 0.f;
#pragma unroll
  for (int d8 = 0; d8 < 16; ++d8) {
    bf16x8_t qv = q8[d8];
    bf16x8_t kv = k8[H * 16 + (d8 ^ (H & 7))];
#pragma unroll
    for (int j = 0; j < 8; ++j)
      s = fmaf((float)qv[j], (float)kv[j], s);
  }
  s *= 0.08838834764831843f;

  float mx = s;
#pragma unroll
  for (int o = 8; o; o >>= 1) mx = fmaxf(mx, __shfl_xor(mx, o));
  const float e = __expf(s - mx);
  float sum = e;
#pragma unroll
  for (int o = 8; o; o >>= 1) sum += __shfl_xor(sum, o);
  sW[h][H] = e / sum;
  __syncthreads();

  const int d0c = t & 15;
  const bf16x8_t* v8 = (const bf16x8_t*)sQKV + 512;
  float accv[8] = {};
#pragma unroll
  for (int j = 0; j < 16; ++j) {
    const float w = sW[h][j];
    const bf16x8_t vv = v8[j * 16 + d0c];
#pragma unroll
    for (int jj = 0; jj < 8; ++jj)
      accv[jj] = fmaf(w, (float)vv[jj], accv[jj]);
  }
  bf16x8_t o;
#pragma unroll
  for (int jj = 0; jj < 8; ++jj) o[jj] = (__bf16)accv[jj];
  *(bf16x8_t*)(attn + (size_t)blockIdx.x * EMB + h * 128 + d0c * 8) = o;
}

// ---------------------------------------------------------------- launch
extern "C" void kernel_launch(void* const* d_in, const int* in_sizes, int n_in,
                              void* d_out, int out_size, void* d_ws, size_t ws_size,
                              hipStream_t stream) {
  const float* x    = (const float*)d_in[0];
  const float* Wqkv = (const float*)d_in[1];
  const float* Wout = (const float*)d_in[2];
  const float* bout = (const float*)d_in[3];
  float* out = (float*)d_out;

  unsigned short* xb    = (unsigned short*)d_ws;          // 33,554,432
  unsigned short* wqkvT = xb    + (size_t)33554432;       // 12,582,912
  unsigned short* woutT = wqkvT + (size_t)12582912;       //  4,194,304
  unsigned short* qkv   = woutT + (size_t)4194304;        // 100,663,296
  unsigned short* attn  = qkv   + (size_t)100663296;      // 33,554,432

  prep<<<18432, 256, 0, stream>>>((const float4*)x, (ushort4*)xb,
                                  Wqkv, wqkvT, Wout, woutT);
  // qkv = x @ W_qkv : grid 64*24 = 1536 (%8==0)
  gemm_bt<true><<<(16384 / 256) * (6144 / 256), 512, 0, stream>>>(
      xb, wqkvT, qkv, nullptr, nullptr, 16384, 6144);
  attn_heads<<<TOKENS, 256, 0, stream>>>(qkv, attn);
  // out = attn @ W_out + b_out : grid 64*8 = 512 (%8==0)
  gemm_bt<false><<<(16384 / 256) * (2048 / 256), 512, 0, stream>>>(
      attn, woutT, nullptr, out, bout, 16384, 2048);
}

// Round 15
// 583.131 us; speedup vs baseline: 1.2447x; 1.0259x over previous
//
#include <hip/hip_runtime.h>
#include <hip/hip_bf16.h>
#include <cstdint>

// B=4, S=4096, E=2048, H=16, D=128 -> 16384 independent tokens.
// qkv = x @ W_qkv (16384x2048x6144); per-token 16x16 head mix;
// out = attn @ W_out + b_out (16384x2048x2048).

#define TOKENS 16384
#define EMB    2048
#define NQKV   6144

typedef __bf16 bf16x8_t __attribute__((ext_vector_type(8)));
typedef float  f32x4_t  __attribute__((ext_vector_type(4)));
typedef unsigned short ushort8_t __attribute__((ext_vector_type(8)));

#define GLOAD16(gsrc, ldst)                                                    \
  __builtin_amdgcn_global_load_lds(                                            \
      (const __attribute__((address_space(1))) void*)(uintptr_t)(gsrc),        \
      (__attribute__((address_space(3))) void*)(uint32_t)(uintptr_t)(ldst),    \
      16, 0, 0)

static __device__ __forceinline__ unsigned short f32_to_bf16_bits(float f) {
  union { float f; uint32_t u; } x; x.f = f;
  uint32_t u = x.u;
  u += 0x7fffu + ((u >> 16) & 1u);   // round-to-nearest-even
  return (unsigned short)(u >> 16);
}

static __device__ __forceinline__ unsigned int pack_bf16(float lo, float hi) {
  return ((unsigned int)f32_to_bf16_bits(hi) << 16) | (unsigned int)f32_to_bf16_bits(lo);
}

// ------------------------------------------------- merged prep kernel
__global__ __launch_bounds__(256) void prep(
    const float4* __restrict__ x4, ushort4* __restrict__ xb4,
    const float* __restrict__ Wqkv, unsigned short* __restrict__ wqkvT,
    const float* __restrict__ Wout, unsigned short* __restrict__ woutT) {
  const int b = blockIdx.x;
  const int t = threadIdx.x;
  if (b < 2048) {
    const int n4 = 33554432 / 4;
    const int stride = 2048 * 256;
    for (int i = b * 256 + t; i < n4; i += stride) {
      float4 v = x4[i];
      ushort4 o;
      o.x = f32_to_bf16_bits(v.x);
      o.y = f32_to_bf16_bits(v.y);
      o.z = f32_to_bf16_bits(v.z);
      o.w = f32_to_bf16_bits(v.w);
      xb4[i] = o;
    }
    return;
  }
  __shared__ float tile[32][33];
  const float* in;
  unsigned short* out;
  int R, C, bxt, byt;
  if (b < 14336) {
    const int bb = b - 2048;
    in = Wqkv; out = wqkvT; R = 2048; C = 6144;
    bxt = bb % 192; byt = bb / 192;
  } else {
    const int bb = b - 14336;
    in = Wout; out = woutT; R = 2048; C = 2048;
    bxt = bb % 64; byt = bb / 64;
  }
  const int bx = bxt * 32;
  const int by = byt * 32;
  const int tx = t & 31;
  const int ty = t >> 5;   // 0..7
#pragma unroll
  for (int j = 0; j < 32; j += 8)
    tile[ty + j][tx] = in[(size_t)(by + ty + j) * C + bx + tx];
  __syncthreads();
#pragma unroll
  for (int j = 0; j < 32; j += 8)
    out[(size_t)(bx + ty + j) * R + by + tx] = f32_to_bf16_bits(tile[tx][ty + j]);
}

// ---------------------------------------------------------------- GEMM
// (R14 kernel, unchanged: wave-group role stagger, best measured 365 us / 54%)
template <bool OUT_BF16>
__global__ __launch_bounds__(512, 1) void gemm_bt(
    const unsigned short* __restrict__ A,
    const unsigned short* __restrict__ BT,
    unsigned short* __restrict__ Cb,
    float* __restrict__ Cf,
    const float* __restrict__ bias,
    int M, int N) {
  constexpr int K = 2048;
  constexpr int BK = 64;
  constexpr int NKT = K / BK;          // 32
  __shared__ __align__(16) char lds[131072];  // [2 bufs][A 32KB | B 32KB]

  const int nbx = N / 256;
  const int nwg = gridDim.x;           // % 8 == 0
  const int bid = blockIdx.x;
  const int swzb = (bid & 7) * (nwg >> 3) + (bid >> 3);
  const int by = swzb / nbx;
  const int bx = swzb % nbx;

  const int t    = threadIdx.x;
  const int lane = t & 63;
  const int wid  = t >> 6;             // 0..7
  const int wr   = wid >> 2;           // 0..1 (M)  -> group id
  const int wc   = wid & 3;            // 0..3 (N)
  const int lr   = lane & 15;
  const int g    = lane >> 4;          // 0..3
  const bool g0  = (wr == 0);

  const unsigned short* aSrc = A  + (size_t)by * 256 * K;
  const unsigned short* bSrc = BT + (size_t)bx * 256 * K;

  int aoff[2], boff[2];
#pragma unroll
  for (int i = 0; i < 2; ++i) {
    const int p   = (i * 512 + t) * 16;
    const int lo  = p ^ (((p >> 7) & 7) << 4);
    const int rih = lo >> 7;
    const int kbe = (lo & 127) >> 1;
    aoff[i] = (((rih >> 6) << 7) + (rih & 63)) * K + kbe;
    boff[i] = (((rih >> 5) << 6) + (rih & 31)) * K + kbe;
  }
  const int ldst = wid << 10;

  auto stageA = [&](int h, int k0, char* bufA) {
#pragma unroll
    for (int i = 0; i < 2; ++i)
      GLOAD16(aSrc + aoff[i] + h * (64 * K) + k0, bufA + h * 16384 + i * 8192 + ldst);
  };
  auto stageB = [&](int h, int k0, char* bufB) {
#pragma unroll
    for (int i = 0; i < 2; ++i)
      GLOAD16(bSrc + boff[i] + h * (32 * K) + k0, bufB + h * 16384 + i * 8192 + ldst);
  };

  const int sw   = (lr & 7) << 4;
  const int col0 = (g * 16) ^ sw;
  const int col1 = (64 + g * 16) ^ sw;
  const int aRow = (wr * 64 + lr) * 128;
  const int bRow = (wc * 32 + lr) * 128;

  f32x4_t acc[8][4] = {};
  bf16x8_t av[4][2];                   // A quadrant frags [m2][ks], reused q0/q1
  bf16x8_t bv0[2][2], bv1[2][2];       // B pair frags [e][ks]

#define LDA_INTO(dst, bufA_, q)                                                \
  {                                                                            \
    const char* _b = (bufA_) + (q) * 16384 + aRow;                             \
    _Pragma("unroll") for (int m2 = 0; m2 < 4; ++m2) {                         \
      dst[m2][0] = *(const bf16x8_t*)(_b + m2 * 2048 + col0);                  \
      dst[m2][1] = *(const bf16x8_t*)(_b + m2 * 2048 + col1);                  \
    }                                                                          \
  }
#define LDB_INTO(dst, bufB_, pair)                                             \
  {                                                                            \
    _Pragma("unroll") for (int e = 0; e < 2; ++e) {                            \
      const int nf = (pair) * 2 + e;                                           \
      const char* _b = (bufB_) + (nf >> 1) * 16384 + (nf & 1) * 2048 + bRow;   \
      dst[e][0] = *(const bf16x8_t*)(_b + col0);                               \
      dst[e][1] = *(const bf16x8_t*)(_b + col1);                               \
    }                                                                          \
  }
#define MFMAQ(AV, BV, Q, PAIR)                                                 \
  _Pragma("unroll") for (int m2 = 0; m2 < 4; ++m2)                             \
  _Pragma("unroll") for (int e = 0; e < 2; ++e)                                \
  _Pragma("unroll") for (int ks = 0; ks < 2; ++ks)                             \
    acc[(Q) * 4 + m2][(PAIR) * 2 + e] = __builtin_amdgcn_mfma_f32_16x16x32_bf16( \
        AV[m2][ks], BV[e][ks], acc[(Q) * 4 + m2][(PAIR) * 2 + e], 0, 0, 0);

#define SBR __builtin_amdgcn_sched_barrier(0)
#define BARR __builtin_amdgcn_s_barrier()
#define LGKM0 asm volatile("s_waitcnt lgkmcnt(0)" ::: "memory"); SBR;
#define P1_ __builtin_amdgcn_s_setprio(1);
#define P0_ __builtin_amdgcn_s_setprio(0); SBR;

#define MQ0 { LGKM0; P1_; MFMAQ(av, bv0, 0, 0); MFMAQ(av, bv1, 0, 1); P0_; }
#define MQ1 { LGKM0; P1_; MFMAQ(av, bv0, 1, 0); MFMAQ(av, bv1, 1, 1); P0_; }

#define BODY(KT, SA1, SB2, VMN, MP)                                            \
  {                                                                            \
    char* cA = lds + ((KT) & 1) * 65536;                                       \
    char* cB = cA + 32768;                                                     \
    char* nA = lds + (((KT) + 1) & 1) * 65536;                                 \
    const int k1 = ((KT) + 1) * BK, k2 = ((KT) + 2) * BK;                      \
    if (g0) { LDA_INTO(av, cA, 0); LDB_INTO(bv0, cB, 0); LDB_INTO(bv1, cB, 1); } \
    SBR;                                                                       \
    if (SA1) { stageA(0, k1, nA); } SBR;                                       \
    if (!g0 && (MP)) MQ1;                                                      \
    SBR; BARR;                                                                 \
    if (!g0) { LDA_INTO(av, cA, 0); LDB_INTO(bv0, cB, 0); LDB_INTO(bv1, cB, 1); } \
    SBR;                                                                       \
    if (SA1) { stageA(1, k1, nA); } SBR;                                       \
    if (g0) MQ0;                                                               \
    SBR; BARR;                                                                 \
    if (g0) { LDA_INTO(av, cA, 1); } SBR;                                      \
    if (!g0) MQ0;                                                              \
    SBR; BARR;                                                                 \
    if (!g0) { LDA_INTO(av, cA, 1); } SBR;                                     \
    if (SB2) { stageB(0, k2, cB); stageB(1, k2, cB); } SBR;                    \
    asm volatile("s_waitcnt vmcnt(" #VMN ")" ::: "memory"); SBR;               \
    if (g0) MQ1;                                                               \
    SBR; BARR;                                                                 \
  }

  {
    char* b0A = lds;
    char* b0B = lds + 32768;
    char* b1B = lds + 65536 + 32768;
    stageB(0, 0, b0B); stageB(1, 0, b0B);
    stageA(0, 0, b0A);
    stageA(1, 0, b0A);
    stageB(0, BK, b1B); stageB(1, BK, b1B);
    asm volatile("s_waitcnt vmcnt(4)" ::: "memory");
    BARR;
  }

  BODY(0, 1, 1, 4, 0);
  for (int kt = 1; kt < NKT - 2; ++kt) {
    BODY(kt, 1, 1, 4, 1);
  }
  BODY(NKT - 2, 1, 0, 0, 1);
  BODY(NKT - 1, 0, 0, 0, 1);
  if (!g0) MQ1;

  const int rbase = by * 256 + wr * 128 + g * 4;
  const int cbase = bx * 256 + wc * 64 + lr;
#pragma unroll
  for (int m = 0; m < 8; ++m) {
#pragma unroll
    for (int nf = 0; nf < 4; ++nf) {
      const int col = cbase + nf * 16;
#pragma unroll
      for (int j = 0; j < 4; ++j) {
        const size_t off = (size_t)(rbase + (m >> 2) * 64 + (m & 3) * 16 + j) * N + col;
        if constexpr (OUT_BF16) {
          Cb[off] = f32_to_bf16_bits(acc[m][nf][j]);
        } else {
          Cf[off] = acc[m][nf][j] + bias[col];
        }
      }
    }
  }
#undef LDA_INTO
#undef LDB_INTO
#undef MFMAQ
#undef SBR
#undef BARR
#undef LGKM0
#undef P1_
#undef P0_
#undef MQ0
#undef MQ1
#undef BODY
}

// ---------------------------------------------------------------- attention
// MFMA attention: ONE WAVE PER TOKEN, no barriers.
//   S^T = mfma(A=K, B=Q) x4 chunks (both operands contiguous bf16x8 global
//   gathers).  D-layout: col = h = lane&15, row = H = (lane>>4)*4+r.
//   Softmax over H: 4 regs + shfl_xor(16/32).  P^T distributed into the
//   B-operand layout via 4 packed shfls; normalization deferred (x 1/sum[h]
//   post-MFMA, sum is in-lane since out col == h).
//   PV: attn^T = V^T . P^T via 8x mfma_16x16x32 (k=16..31 zero-padded regs).
//   V^T A-frags: 8 ds_read_u16 per chunk from a 4KB/wave LDS V slice,
//   word-swap swizzle (byte^=4 iff H>=8) -> 2 lanes/bank, conflict-free.
__global__ __launch_bounds__(256) void attn_mfma(
    const unsigned short* __restrict__ qkv,  // [T][6144] bf16
    unsigned short* __restrict__ attn) {     // [T][2048] bf16
  __shared__ __align__(16) unsigned short sV[4][2048];  // 4 waves x 4KB

  const int t  = threadIdx.x;
  const int w  = t >> 6;
  const int l  = t & 63;
  const int lr = l & 15;
  const int g  = l >> 4;           // 0..3
  const size_t tok = (size_t)blockIdx.x * 4 + w;
  const unsigned short* base = qkv + tok * NQKV;

  // ---- stage V (16x128) to LDS, word-swapped for H>=8 (read-swizzle match)
  {
    const uint4* vg = (const uint4*)(base + 4096);
    uint4* vl = (uint4*)&sV[w][0];
#pragma unroll
    for (int i = 0; i < 4; ++i) {
      const int idx = i * 64 + l;        // 256 uint4 = 16 rows x 16
      uint4 v = vg[idx];
      if (idx & 128) {                   // H = idx>>4; H&8 <=> idx&128
        uint4 o; o.x = v.y; o.y = v.x; o.z = v.w; o.w = v.z;
        vl[idx] = o;
      } else {
        vl[idx] = v;
      }
    }
  }

  // ---- QK^T -> S^T fragment (col=h=lr, row=H=g*4+r)
  f32x4_t s = {};
#pragma unroll
  for (int ch = 0; ch < 4; ++ch) {
    bf16x8_t ka = *(const bf16x8_t*)(base + 2048 + lr * 128 + ch * 32 + g * 8);
    bf16x8_t qb = *(const bf16x8_t*)(base +        lr * 128 + ch * 32 + g * 8);
    s = __builtin_amdgcn_mfma_f32_16x16x32_bf16(ka, qb, s, 0, 0, 0);
  }

  // ---- softmax over H (regs + lanes l^16, l^32); P unnormalized (<=1)
  float p0 = s[0] * 0.08838834764831843f;
  float p1 = s[1] * 0.08838834764831843f;
  float p2 = s[2] * 0.08838834764831843f;
  float p3 = s[3] * 0.08838834764831843f;
  float mx = fmaxf(fmaxf(p0, p1), fmaxf(p2, p3));
  mx = fmaxf(mx, __shfl_xor(mx, 16));
  mx = fmaxf(mx, __shfl_xor(mx, 32));
  p0 = __expf(p0 - mx);
  p1 = __expf(p1 - mx);
  p2 = __expf(p2 - mx);
  p3 = __expf(p3 - mx);
  float sum = p0 + p1 + p2 + p3;
  sum += __shfl_xor(sum, 16);
  sum += __shfl_xor(sum, 32);
  const float inv = 1.0f / sum;

  // ---- distribute P^T into B-frag layout: lane needs P[h=lr][H=g*8+jj]
  const unsigned int u01 = pack_bf16(p0, p1);
  const unsigned int u23 = pack_bf16(p2, p3);
  const int gs = (g & 1) * 2;                  // 2g clamped for g>=2
  const int m1 = (gs << 4) | lr;
  const int m2 = m1 + 16;
  union { uint4 u; bf16x8_t b; } pB;
  pB.u.x = __shfl(u01, m1);
  pB.u.y = __shfl(u23, m1);
  pB.u.z = __shfl(u01, m2);
  pB.u.w = __shfl(u23, m2);
  if (g >= 2) { pB.u.x = 0; pB.u.y = 0; pB.u.z = 0; pB.u.w = 0; }

  // ---- PV: 8 d-chunks; A = V^T frag (8 swizzled u16, zero for g>=2)
  const char* vbase = (const char*)&sV[w][0];
  const int dbyte = (lr * 2) ^ (g < 2 ? (g << 2) : 0);
#pragma unroll
  for (int ch = 0; ch < 8; ++ch) {
    union { ushort8_t u; bf16x8_t b; } va;
    if (g < 2) {
#pragma unroll
      for (int j = 0; j < 8; ++j) {
        const int H = g * 8 + j;
        va.u[j] = *(const unsigned short*)(vbase + H * 256 + ch * 32 + dbyte);
      }
    } else {
      va.u = (ushort8_t){0, 0, 0, 0, 0, 0, 0, 0};
    }
    f32x4_t z = {};
    f32x4_t o = __builtin_amdgcn_mfma_f32_16x16x32_bf16(va.b, pB.b, z, 0, 0, 0);
    // D: col=h=lr, rows d_local = g*4+r  ->  4 consecutive d
    uint2 st;
    st.x = pack_bf16(o[0] * inv, o[1] * inv);
    st.y = pack_bf16(o[2] * inv, o[3] * inv);
    *(uint2*)(attn + tok * EMB + lr * 128 + ch * 16 + g * 4) = st;
  }
}

// ---------------------------------------------------------------- launch
extern "C" void kernel_launch(void* const* d_in, const int* in_sizes, int n_in,
                              void* d_out, int out_size, void* d_ws, size_t ws_size,
                              hipStream_t stream) {
  const float* x    = (const float*)d_in[0];
  const float* Wqkv = (const float*)d_in[1];
  const float* Wout = (const float*)d_in[2];
  const float* bout = (const float*)d_in[3];
  float* out = (float*)d_out;

  unsigned short* xb    = (unsigned short*)d_ws;          // 33,554,432
  unsigned short* wqkvT = xb    + (size_t)33554432;       // 12,582,912
  unsigned short* woutT = wqkvT + (size_t)12582912;       //  4,194,304
  unsigned short* qkv   = woutT + (size_t)4194304;        // 100,663,296
  unsigned short* attn  = qkv   + (size_t)100663296;      // 33,554,432

  prep<<<18432, 256, 0, stream>>>((const float4*)x, (ushort4*)xb,
                                  Wqkv, wqkvT, Wout, woutT);
  // qkv = x @ W_qkv : grid 64*24 = 1536 (%8==0)
  gemm_bt<true><<<(16384 / 256) * (6144 / 256), 512, 0, stream>>>(
      xb, wqkvT, qkv, nullptr, nullptr, 16384, 6144);
  // per-token head mixing: 1 wave per token, 4 tokens per block
  attn_mfma<<<TOKENS / 4, 256, 0, stream>>>(qkv, attn);
  // out = attn @ W_out + b_out : grid 64*8 = 512 (%8==0)
  gemm_bt<false><<<(16384 / 256) * (2048 / 256), 512, 0, stream>>>(
      attn, woutT, nullptr, out, bout, 16384, 2048);
}